// Round 12
// baseline (156.349 us; speedup 1.0000x reference)
//
#include <hip/hip_runtime.h>
#include <hip/hip_bf16.h>

#define DFEAT   128
#define BCAP    2048         // edge capacity per 64-node bucket (avg ~1024, 32 sigma margin)
#define NB_MAX  1024

typedef __attribute__((ext_vector_type(8))) short bf16x8;
typedef __attribute__((ext_vector_type(4))) float f32x4;
typedef unsigned int uint;

// ---------------- single-pass dst-bucketed edge scatter ----------------
// bucket = dst >> 6. payload: (src | dstLocal<<26, weight_bits)

__global__ __launch_bounds__(1024) void bin_scatter(const int* __restrict__ src,
                                                    const int* __restrict__ dst,
                                                    const float* __restrict__ ew,
                                                    int* __restrict__ cursor,
                                                    int2* __restrict__ bedges,
                                                    int E, int NB) {
    __shared__ int hist[NB_MAX];
    __shared__ int base[NB_MAX];
    const int tid = threadIdx.x;
    for (int b = tid; b < NB; b += 1024) hist[b] = 0;
    __syncthreads();

    int  s[8]; float w[8]; int bk[8]; int dl[8];
    const int i0 = blockIdx.x * 8192 + tid;
    #pragma unroll
    for (int k = 0; k < 8; ++k) {
        int i = i0 + k * 1024;
        if (i < E) {
            s[k] = src[i]; w[k] = ew[i];
            int d = dst[i];
            bk[k] = d >> 6; dl[k] = d & 63;
            atomicAdd(&hist[bk[k]], 1);
        } else bk[k] = -1;
    }
    __syncthreads();
    for (int b = tid; b < NB; b += 1024) {
        int c = hist[b];
        base[b] = (c > 0) ? atomicAdd(&cursor[b], c) : 0;
        hist[b] = 0;                       // reuse as rank counter
    }
    __syncthreads();
    #pragma unroll
    for (int k = 0; k < 8; ++k) {
        if (bk[k] >= 0) {
            int r = atomicAdd(&hist[bk[k]], 1);
            int pos = base[bk[k]] + r;
            if (pos < ((bk[k] + 1) << 11)) {   // overflow guard (never triggers)
                bedges[pos] = make_int2(s[k] | (dl[k] << 26), __float_as_int(w[k]));
            }
        }
    }
}

// ---------------- per-bucket LDS counting sort (in place) + rowptr/rowend ----------------

__global__ __launch_bounds__(1024) void bucket_sort(const int* __restrict__ cursor,
                                                    int2* __restrict__ bedges,
                                                    int* __restrict__ rowptr,
                                                    int* __restrict__ rowend, int N) {
    __shared__ int2 buf[BCAP];                 // 16 KB
    __shared__ int hist[64], pref[64], rank[64];
    const int b = blockIdx.x, tid = threadIdx.x;
    const int base = b << 11;                  // b * BCAP
    const int cnt = cursor[b] - base;

    if (tid < 64) hist[tid] = 0;
    __syncthreads();
    for (int i = tid; i < cnt; i += 1024) {
        int2 e = bedges[base + i];
        buf[i] = e;
        atomicAdd(&hist[((uint)e.x) >> 26], 1);
    }
    __syncthreads();
    if (tid < 64) {
        int v = hist[tid];
        int s = v;
        #pragma unroll
        for (int off = 1; off < 64; off <<= 1) {
            int t = __shfl_up(s, off, 64);
            if (tid >= off) s += t;
        }
        pref[tid] = s - v;                     // exclusive prefix
        rank[tid] = 0;
        int node = b * 64 + tid;
        if (node < N) {
            rowptr[node] = base + (s - v);
            rowend[node] = base + s;
        }
    }
    __syncthreads();
    for (int i = tid; i < cnt; i += 1024) {
        int2 e = buf[i];
        int dl = ((uint)e.x) >> 26;
        int r = atomicAdd(&rank[dl], 1);
        bedges[base + pref[dl] + r] = e;
    }
}

// ---------------- helpers ----------------

__device__ __forceinline__ uint pack_bf16x2(float a, float b) {
    __hip_bfloat16 ba = __float2bfloat16(a);
    __hip_bfloat16 bb = __float2bfloat16(b);
    unsigned short ua = *(unsigned short*)&ba;
    unsigned short ub = *(unsigned short*)&bb;
    return (uint)ua | ((uint)ub << 16);
}

__device__ __forceinline__ void fma8(float* acc, uint4 q, float wt) {
    acc[0] = fmaf(wt, __uint_as_float(q.x << 16),         acc[0]);
    acc[1] = fmaf(wt, __uint_as_float(q.x & 0xffff0000u), acc[1]);
    acc[2] = fmaf(wt, __uint_as_float(q.y << 16),         acc[2]);
    acc[3] = fmaf(wt, __uint_as_float(q.y & 0xffff0000u), acc[3]);
    acc[4] = fmaf(wt, __uint_as_float(q.z << 16),         acc[4]);
    acc[5] = fmaf(wt, __uint_as_float(q.z & 0xffff0000u), acc[5]);
    acc[6] = fmaf(wt, __uint_as_float(q.w << 16),         acc[6]);
    acc[7] = fmaf(wt, __uint_as_float(q.w & 0xffff0000u), acc[7]);
}

// ---------------- merged prep: cvt (x->bf16) + weight pack x3 + cursor init ----------------

__global__ void prep_all(const float* __restrict__ x, uint* __restrict__ xb, int n2,
                         const float* __restrict__ w1r, const float* __restrict__ w1t,
                         const float* __restrict__ w2r, const float* __restrict__ w2t,
                         const float* __restrict__ w3r, const float* __restrict__ w3t,
                         __hip_bfloat16* __restrict__ Bp1, __hip_bfloat16* __restrict__ Bp2,
                         __hip_bfloat16* __restrict__ Bp3,
                         int* __restrict__ cursor, int NB, int cvtB) {
    const int b = blockIdx.x, tid = threadIdx.x;
    if (b < cvtB) {
        int i = b * 256 + tid;
        if (i < n2) {
            float2 v = ((const float2*)x)[i];
            xb[i] = pack_bf16x2(v.x, v.y);
        }
    } else if (b < cvtB + 384) {
        const int b2 = b - cvtB;
        const int g = b2 >> 7;                       // layer 0,1,2
        const int idx = (b2 & 127) * 256 + tid;      // 0..32767
        const float* wrel  = (g == 0) ? w1r : (g == 1) ? w2r : w3r;
        const float* wroot = (g == 0) ? w1t : (g == 1) ? w2t : w3t;
        __hip_bfloat16* Bp = (g == 0) ? Bp1 : (g == 1) ? Bp2 : Bp3;
        int j     = idx & 7;
        int lane  = (idx >> 3) & 63;
        int nfrag = (idx >> 9) & 7;
        int kstep = idx >> 12;
        int k = kstep * 32 + (lane >> 4) * 8 + j;
        int n = nfrag * 16 + (lane & 15);
        float v = (k < 128) ? wrel[n * 128 + k] : wroot[n * 128 + (k - 128)];
        Bp[idx] = __float2bfloat16(v);
    } else {
        int i = (b - cvtB - 384) * 256 + tid;
        if (i < NB) cursor[i] = i * BCAP;
    }
}

// ---------------- fused layer: 32-node tile, 8 waves, pipelined agg -> LDS -> MFMA ------
// Block = 32 nodes, 512 threads (8 waves), 4 nodes/wave.
// Phase 1 (per wave): node q+1's metadata load issued before node q's edges are consumed;
//   inside the edge loop the next 8-edge pair's gathers issue before the current pair's
//   FMAs (pair-ahead). 16 lanes/edge, dwordx4 row slices.
// Phase 2: C[32,128] = [aggLDS | root][32,256] @ Bcat[256,128] + bias via MFMA;
//   waves 2x4: wr=wid>>2 (16 rows), wc=wid&3 (32 cols), 2 frags/wave.

template<int RELU, int OUTF32>
__global__ __launch_bounds__(512) void fused_layer(const uint* __restrict__ f,
                                                   const int* __restrict__ rowptr,
                                                   const int* __restrict__ rowend,
                                                   const int2* __restrict__ bedges,
                                                   const bf16x8* __restrict__ Bp,
                                                   const float* __restrict__ bias,
                                                   float* __restrict__ outf,
                                                   __hip_bfloat16* __restrict__ outb,
                                                   int N) {
    __shared__ uint4 As4[32][17];                  // 8704 B, row stride 272B
    const int tid  = threadIdx.x;
    const int lane = tid & 63, wid = tid >> 6;     // wid 0..7
    const int grp  = lane >> 4;
    const int sub  = lane & 15;
    const int tile = blockIdx.x * 32;
    const uint4* f4 = (const uint4*)f;

    // prefetch this wave's 4 rowptr/rowend (lane-parallel)
    const int pn = tile + wid * 4 + (lane & 3);
    int rp = 0, re = 0;
    if (lane < 4 && pn < N) { rp = rowptr[pn]; re = rowend[pn]; }

    // prefetch first-chunk metadata for node 0
    int begC = __builtin_amdgcn_readlane(rp, 0);
    int degC = __builtin_amdgcn_readlane(re, 0) - begC;
    int2 eCur = make_int2(0, 0);
    if (degC > 0) eCur = bedges[begC + min(lane, min(degC, 64) - 1)];

    // ---- phase 1: 4 nodes per wave, metadata pipelined one node ahead ----
    for (int qn = 0; qn < 4; ++qn) {
        const int beg = begC, deg = degC;
        int2 eNext = make_int2(0, 0);
        if (qn < 3) {
            begC = __builtin_amdgcn_readlane(rp, qn + 1);
            degC = __builtin_amdgcn_readlane(re, qn + 1) - begC;
            if (degC > 0) eNext = bedges[begC + min(lane, min(degC, 64) - 1)];
        }

        float acc[8];
        #pragma unroll
        for (int i = 0; i < 8; ++i) acc[i] = 0.f;

        int done = 0;
        int2 e = eCur;
        while (done < deg) {
            const int chunk = min(deg - done, 64);
            if (done) e = bedges[beg + done + min(lane, chunk - 1)];   // rare (deg > 64)
            const int vsrc = e.x & 0x03FFFFFF;
            const int vwb  = (lane < chunk) ? e.y : 0;   // 0 bits == 0.0f
            const int iters = (chunk + 7) & ~7;
            // prologue pair (edges j=0..7)
            int   s0 = __shfl(vsrc, grp, 64);
            float w0 = __int_as_float(__shfl(vwb, grp, 64));
            int   s1 = __shfl(vsrc, 4 + grp, 64);
            float w1 = __int_as_float(__shfl(vwb, 4 + grp, 64));
            uint4 q0 = f4[(size_t)s0 * 16 + sub];
            uint4 q1 = f4[(size_t)s1 * 16 + sub];
            for (int j = 8; j < iters; j += 8) {
                // issue next pair before consuming current
                int   s2 = __shfl(vsrc, j + grp, 64);
                float w2 = __int_as_float(__shfl(vwb, j + grp, 64));
                int   s3 = __shfl(vsrc, j + 4 + grp, 64);
                float w3 = __int_as_float(__shfl(vwb, j + 4 + grp, 64));
                uint4 q2 = f4[(size_t)s2 * 16 + sub];
                uint4 q3 = f4[(size_t)s3 * 16 + sub];
                fma8(acc, q0, w0); fma8(acc, q1, w1);
                q0 = q2; q1 = q3; w0 = w2; w1 = w3;
            }
            fma8(acc, q0, w0); fma8(acc, q1, w1);
            done += chunk;
        }

        // combine the 4 edge-groups (lanes sharing `sub`)
        #pragma unroll
        for (int i = 0; i < 8; ++i) {
            acc[i] += __shfl_xor(acc[i], 16, 64);
            acc[i] += __shfl_xor(acc[i], 32, 64);
        }
        if (lane < 16) {
            uint4 o;
            o.x = pack_bf16x2(acc[0], acc[1]);
            o.y = pack_bf16x2(acc[2], acc[3]);
            o.z = pack_bf16x2(acc[4], acc[5]);
            o.w = pack_bf16x2(acc[6], acc[7]);
            As4[wid * 4 + qn][sub] = o;
        }
        eCur = eNext;
    }
    __syncthreads();

    // ---- phase 2: GEMM, waves 2x4 (wr: 16-row group, wc: 32-col group) ----
    const int wr = wid >> 2, wc = wid & 3;
    const int lrow = lane & 15;
    const int lkq  = (lane >> 4);
    const short* As_s = (const short*)&As4[0][0];   // row stride = 136 shorts
    const short* fb   = (const short*)f;

    int gr = tile + wr * 16 + lrow;
    if (gr >= N) gr = N - 1;

    f32x4 acc2[2];
    acc2[0] = (f32x4){0.f, 0.f, 0.f, 0.f};
    acc2[1] = (f32x4){0.f, 0.f, 0.f, 0.f};

    #pragma unroll
    for (int ks = 0; ks < 8; ++ks) {
        bf16x8 a;
        if (ks < 4)
            a = *(const bf16x8*)(As_s + (wr * 16 + lrow) * 136 + ks * 32 + lkq * 8);
        else
            a = *(const bf16x8*)(fb + (size_t)gr * 128 + (ks - 4) * 32 + lkq * 8);
        #pragma unroll
        for (int nf = 0; nf < 2; ++nf) {
            bf16x8 b = Bp[(ks * 8 + (wc * 2 + nf)) * 64 + lane];
            acc2[nf] = __builtin_amdgcn_mfma_f32_16x16x32_bf16(a, b, acc2[nf], 0, 0, 0);
        }
    }

    // ---- epilogue ----
    const int crow = (lane >> 4) * 4;
    const int ccol = lane & 15;
    #pragma unroll
    for (int nf = 0; nf < 2; ++nf) {
        const int col = wc * 32 + nf * 16 + ccol;
        const float bv = bias[col];
        #pragma unroll
        for (int r = 0; r < 4; ++r) {
            const int row = tile + wr * 16 + crow + r;
            if (row < N) {
                float v = acc2[nf][r] + bv;
                if (RELU) v = fmaxf(v, 0.f);
                if (OUTF32) outf[(size_t)row * 128 + col] = v;
                else        outb[(size_t)row * 128 + col] = __float2bfloat16(v);
            }
        }
    }
}

// ---------------- launch ----------------

extern "C" void kernel_launch(void* const* d_in, const int* in_sizes, int n_in,
                              void* d_out, int out_size, void* d_ws, size_t ws_size,
                              hipStream_t stream) {
    const float* x   = (const float*)d_in[0];
    const int*  eidx = (const int*)d_in[1];
    const float* ew  = (const float*)d_in[2];
    const float* w1r = (const float*)d_in[3];
    const float* w1t = (const float*)d_in[4];
    const float* b1  = (const float*)d_in[5];
    const float* w2r = (const float*)d_in[6];
    const float* w2t = (const float*)d_in[7];
    const float* b2  = (const float*)d_in[8];
    const float* w3r = (const float*)d_in[9];
    const float* w3t = (const float*)d_in[10];
    const float* b3  = (const float*)d_in[11];
    float* out = (float*)d_out;

    const int N  = in_sizes[0] / DFEAT;   // 50000
    const int E  = in_sizes[2];           // 800000
    const int NB = (N + 63) / 64;         // 782 buckets

    char* ws = (char*)d_ws;
    size_t off = 0;
    auto alloc = [&](size_t bytes) -> void* {
        off = (off + 255) & ~(size_t)255;
        void* p = ws + off;
        off += bytes;
        return p;
    };
    int*  cursor = (int*)alloc((size_t)NB * 4);
    int*  rowptr = (int*)alloc((size_t)N * 4);
    int*  rowend = (int*)alloc((size_t)N * 4);
    int2* bedges = (int2*)alloc((size_t)NB * BCAP * 8);   // 12.8 MB
    __hip_bfloat16* Bp1 = (__hip_bfloat16*)alloc(32768 * 2);
    __hip_bfloat16* Bp2 = (__hip_bfloat16*)alloc(32768 * 2);
    __hip_bfloat16* Bp3 = (__hip_bfloat16*)alloc(32768 * 2);
    uint* xb   = (uint*)alloc((size_t)N * 64 * 4);
    uint* h1b  = (uint*)alloc((size_t)N * 64 * 4);
    uint* h2b  = (uint*)alloc((size_t)N * 64 * 4);
    (void)ws_size;

    const int* src = eidx;
    const int* dst = eidx + E;

    // merged prep: cvt + weight pack + cursor init
    const int n2 = N * 64;
    const int cvtB = (n2 + 255) / 256;
    const int curB = (NB + 255) / 256;
    prep_all<<<cvtB + 384 + curB, 256, 0, stream>>>(x, xb, n2,
                                                    w1r, w1t, w2r, w2t, w3r, w3t,
                                                    Bp1, Bp2, Bp3, cursor, NB, cvtB);

    // CSR build: bucket scatter + per-bucket counting sort
    bin_scatter<<<(E + 8191) / 8192, 1024, 0, stream>>>(src, dst, ew, cursor, bedges, E, NB);
    bucket_sort<<<NB, 1024, 0, stream>>>(cursor, bedges, rowptr, rowend, N);

    // fused layers (32-node tiles)
    const int NB2 = (N + 31) / 32;   // 1563
    fused_layer<1, 0><<<NB2, 512, 0, stream>>>(xb, rowptr, rowend, bedges, (const bf16x8*)Bp1,
                                               b1, nullptr, (__hip_bfloat16*)h1b, N);
    fused_layer<1, 0><<<NB2, 512, 0, stream>>>(h1b, rowptr, rowend, bedges, (const bf16x8*)Bp2,
                                               b2, nullptr, (__hip_bfloat16*)h2b, N);
    fused_layer<0, 1><<<NB2, 512, 0, stream>>>(h2b, rowptr, rowend, bedges, (const bf16x8*)Bp3,
                                               b3, out, nullptr, N);
}

// Round 13
// 151.160 us; speedup vs baseline: 1.0343x; 1.0343x over previous
//
#include <hip/hip_runtime.h>
#include <hip/hip_bf16.h>

#define DFEAT   128
#define BCAP    2048         // edge capacity per 64-node bucket (avg ~1024, 32 sigma margin)
#define NB_MAX  1024

typedef __attribute__((ext_vector_type(8))) short bf16x8;
typedef __attribute__((ext_vector_type(4))) float f32x4;
typedef unsigned int uint;

// ---------------- single-pass dst-bucketed edge scatter ----------------
// bucket = dst >> 6. payload: (src | dstLocal<<26, weight_bits)

__global__ __launch_bounds__(1024) void bin_scatter(const int* __restrict__ src,
                                                    const int* __restrict__ dst,
                                                    const float* __restrict__ ew,
                                                    int* __restrict__ cursor,
                                                    int2* __restrict__ bedges,
                                                    int E, int NB) {
    __shared__ int hist[NB_MAX];
    __shared__ int base[NB_MAX];
    const int tid = threadIdx.x;
    for (int b = tid; b < NB; b += 1024) hist[b] = 0;
    __syncthreads();

    int  s[8]; float w[8]; int bk[8]; int dl[8];
    const int i0 = blockIdx.x * 8192 + tid;
    #pragma unroll
    for (int k = 0; k < 8; ++k) {
        int i = i0 + k * 1024;
        if (i < E) {
            s[k] = src[i]; w[k] = ew[i];
            int d = dst[i];
            bk[k] = d >> 6; dl[k] = d & 63;
            atomicAdd(&hist[bk[k]], 1);
        } else bk[k] = -1;
    }
    __syncthreads();
    for (int b = tid; b < NB; b += 1024) {
        int c = hist[b];
        base[b] = (c > 0) ? atomicAdd(&cursor[b], c) : 0;
        hist[b] = 0;                       // reuse as rank counter
    }
    __syncthreads();
    #pragma unroll
    for (int k = 0; k < 8; ++k) {
        if (bk[k] >= 0) {
            int r = atomicAdd(&hist[bk[k]], 1);
            int pos = base[bk[k]] + r;
            if (pos < ((bk[k] + 1) << 11)) {   // overflow guard (never triggers)
                bedges[pos] = make_int2(s[k] | (dl[k] << 26), __float_as_int(w[k]));
            }
        }
    }
}

// ---------------- per-bucket LDS counting sort (in place) + rowptr/rowend ----------------

__global__ __launch_bounds__(1024) void bucket_sort(const int* __restrict__ cursor,
                                                    int2* __restrict__ bedges,
                                                    int* __restrict__ rowptr,
                                                    int* __restrict__ rowend, int N) {
    __shared__ int2 buf[BCAP];                 // 16 KB
    __shared__ int hist[64], pref[64], rank[64];
    const int b = blockIdx.x, tid = threadIdx.x;
    const int base = b << 11;                  // b * BCAP
    const int cnt = cursor[b] - base;

    if (tid < 64) hist[tid] = 0;
    __syncthreads();
    for (int i = tid; i < cnt; i += 1024) {
        int2 e = bedges[base + i];
        buf[i] = e;
        atomicAdd(&hist[((uint)e.x) >> 26], 1);
    }
    __syncthreads();
    if (tid < 64) {
        int v = hist[tid];
        int s = v;
        #pragma unroll
        for (int off = 1; off < 64; off <<= 1) {
            int t = __shfl_up(s, off, 64);
            if (tid >= off) s += t;
        }
        pref[tid] = s - v;                     // exclusive prefix
        rank[tid] = 0;
        int node = b * 64 + tid;
        if (node < N) {
            rowptr[node] = base + (s - v);
            rowend[node] = base + s;
        }
    }
    __syncthreads();
    for (int i = tid; i < cnt; i += 1024) {
        int2 e = buf[i];
        int dl = ((uint)e.x) >> 26;
        int r = atomicAdd(&rank[dl], 1);
        bedges[base + pref[dl] + r] = e;
    }
}

// ---------------- helpers ----------------

__device__ __forceinline__ uint pack_bf16x2(float a, float b) {
    __hip_bfloat16 ba = __float2bfloat16(a);
    __hip_bfloat16 bb = __float2bfloat16(b);
    unsigned short ua = *(unsigned short*)&ba;
    unsigned short ub = *(unsigned short*)&bb;
    return (uint)ua | ((uint)ub << 16);
}

__device__ __forceinline__ void fma8(float* acc, uint4 q, float wt) {
    acc[0] = fmaf(wt, __uint_as_float(q.x << 16),         acc[0]);
    acc[1] = fmaf(wt, __uint_as_float(q.x & 0xffff0000u), acc[1]);
    acc[2] = fmaf(wt, __uint_as_float(q.y << 16),         acc[2]);
    acc[3] = fmaf(wt, __uint_as_float(q.y & 0xffff0000u), acc[3]);
    acc[4] = fmaf(wt, __uint_as_float(q.z << 16),         acc[4]);
    acc[5] = fmaf(wt, __uint_as_float(q.z & 0xffff0000u), acc[5]);
    acc[6] = fmaf(wt, __uint_as_float(q.w << 16),         acc[6]);
    acc[7] = fmaf(wt, __uint_as_float(q.w & 0xffff0000u), acc[7]);
}

// ---------------- merged prep: cvt (x->bf16) + weight pack x3 + cursor init ----------------

__global__ void prep_all(const float* __restrict__ x, uint* __restrict__ xb, int n2,
                         const float* __restrict__ w1r, const float* __restrict__ w1t,
                         const float* __restrict__ w2r, const float* __restrict__ w2t,
                         const float* __restrict__ w3r, const float* __restrict__ w3t,
                         __hip_bfloat16* __restrict__ Bp1, __hip_bfloat16* __restrict__ Bp2,
                         __hip_bfloat16* __restrict__ Bp3,
                         int* __restrict__ cursor, int NB, int cvtB) {
    const int b = blockIdx.x, tid = threadIdx.x;
    if (b < cvtB) {
        int i = b * 256 + tid;
        if (i < n2) {
            float2 v = ((const float2*)x)[i];
            xb[i] = pack_bf16x2(v.x, v.y);
        }
    } else if (b < cvtB + 384) {
        const int b2 = b - cvtB;
        const int g = b2 >> 7;                       // layer 0,1,2
        const int idx = (b2 & 127) * 256 + tid;      // 0..32767
        const float* wrel  = (g == 0) ? w1r : (g == 1) ? w2r : w3r;
        const float* wroot = (g == 0) ? w1t : (g == 1) ? w2t : w3t;
        __hip_bfloat16* Bp = (g == 0) ? Bp1 : (g == 1) ? Bp2 : Bp3;
        int j     = idx & 7;
        int lane  = (idx >> 3) & 63;
        int nfrag = (idx >> 9) & 7;
        int kstep = idx >> 12;
        int k = kstep * 32 + (lane >> 4) * 8 + j;
        int n = nfrag * 16 + (lane & 15);
        float v = (k < 128) ? wrel[n * 128 + k] : wroot[n * 128 + (k - 128)];
        Bp[idx] = __float2bfloat16(v);
    } else {
        int i = (b - cvtB - 384) * 256 + tid;
        if (i < NB) cursor[i] = i * BCAP;
    }
}

// ---------------- fused layer: 64-node tile, 8 waves, pipelined agg -> LDS -> MFMA ------
// Block = one 64-node bucket, 512 threads (8 waves), 8 nodes/wave.
// Phase 1 (per wave): node q+1's metadata load issued before node q's edges are consumed;
//   inside the edge loop the next 8-edge pair's gathers issue before the current pair's
//   FMAs (pair-ahead). 16 lanes/edge, dwordx4 row slices.
// Phase 2: C[64,128] = [aggLDS | root][64,256] @ Bcat[256,128] + bias via MFMA;
//   waves 2x4: wr=wid>>2 (32 rows), wc=wid&3 (32 cols), each wave 2x2 frags.

template<int RELU, int OUTF32>
__global__ __launch_bounds__(512) void fused_layer(const uint* __restrict__ f,
                                                   const int* __restrict__ rowptr,
                                                   const int* __restrict__ rowend,
                                                   const int2* __restrict__ bedges,
                                                   const bf16x8* __restrict__ Bp,
                                                   const float* __restrict__ bias,
                                                   float* __restrict__ outf,
                                                   __hip_bfloat16* __restrict__ outb,
                                                   int N) {
    __shared__ uint4 As4[64][17];                  // 17408 B, row stride 272B
    const int tid  = threadIdx.x;
    const int lane = tid & 63, wid = tid >> 6;     // wid 0..7
    const int grp  = lane >> 4;
    const int sub  = lane & 15;
    const int tile = blockIdx.x * 64;
    const uint4* f4 = (const uint4*)f;

    // prefetch this wave's 8 rowptr/rowend (lane-parallel)
    const int pn = tile + wid * 8 + (lane & 7);
    int rp = 0, re = 0;
    if (lane < 8 && pn < N) { rp = rowptr[pn]; re = rowend[pn]; }

    // prefetch first-chunk metadata for node 0
    int begC = __builtin_amdgcn_readlane(rp, 0);
    int degC = __builtin_amdgcn_readlane(re, 0) - begC;
    int2 eCur = make_int2(0, 0);
    if (degC > 0) eCur = bedges[begC + min(lane, min(degC, 64) - 1)];

    // ---- phase 1: 8 nodes per wave, metadata pipelined one node ahead ----
    for (int qn = 0; qn < 8; ++qn) {
        const int beg = begC, deg = degC;
        int2 eNext = make_int2(0, 0);
        if (qn < 7) {
            begC = __builtin_amdgcn_readlane(rp, qn + 1);
            degC = __builtin_amdgcn_readlane(re, qn + 1) - begC;
            if (degC > 0) eNext = bedges[begC + min(lane, min(degC, 64) - 1)];
        }

        float acc[8];
        #pragma unroll
        for (int i = 0; i < 8; ++i) acc[i] = 0.f;

        int done = 0;
        int2 e = eCur;
        while (done < deg) {
            const int chunk = min(deg - done, 64);
            if (done) e = bedges[beg + done + min(lane, chunk - 1)];   // rare (deg > 64)
            const int vsrc = e.x & 0x03FFFFFF;
            const int vwb  = (lane < chunk) ? e.y : 0;   // 0 bits == 0.0f
            const int iters = (chunk + 7) & ~7;
            // prologue pair (edges j=0..7)
            int   s0 = __shfl(vsrc, grp, 64);
            float w0 = __int_as_float(__shfl(vwb, grp, 64));
            int   s1 = __shfl(vsrc, 4 + grp, 64);
            float w1 = __int_as_float(__shfl(vwb, 4 + grp, 64));
            uint4 q0 = f4[(size_t)s0 * 16 + sub];
            uint4 q1 = f4[(size_t)s1 * 16 + sub];
            for (int j = 8; j < iters; j += 8) {
                // issue next pair before consuming current
                int   s2 = __shfl(vsrc, j + grp, 64);
                float w2 = __int_as_float(__shfl(vwb, j + grp, 64));
                int   s3 = __shfl(vsrc, j + 4 + grp, 64);
                float w3 = __int_as_float(__shfl(vwb, j + 4 + grp, 64));
                uint4 q2 = f4[(size_t)s2 * 16 + sub];
                uint4 q3 = f4[(size_t)s3 * 16 + sub];
                fma8(acc, q0, w0); fma8(acc, q1, w1);
                q0 = q2; q1 = q3; w0 = w2; w1 = w3;
            }
            fma8(acc, q0, w0); fma8(acc, q1, w1);
            done += chunk;
        }

        // combine the 4 edge-groups (lanes sharing `sub`)
        #pragma unroll
        for (int i = 0; i < 8; ++i) {
            acc[i] += __shfl_xor(acc[i], 16, 64);
            acc[i] += __shfl_xor(acc[i], 32, 64);
        }
        if (lane < 16) {
            uint4 o;
            o.x = pack_bf16x2(acc[0], acc[1]);
            o.y = pack_bf16x2(acc[2], acc[3]);
            o.z = pack_bf16x2(acc[4], acc[5]);
            o.w = pack_bf16x2(acc[6], acc[7]);
            As4[wid * 8 + qn][sub] = o;
        }
        eCur = eNext;
    }
    __syncthreads();

    // ---- phase 2: GEMM, waves 2x4 (wr: 32-row group, wc: 32-col group) ----
    const int wr = wid >> 2, wc = wid & 3;
    const int lrow = lane & 15;
    const int lkq  = (lane >> 4);
    const short* As_s = (const short*)&As4[0][0];   // row stride = 136 shorts
    const short* fb   = (const short*)f;

    int grow[2];
    #pragma unroll
    for (int mi = 0; mi < 2; ++mi) {
        int r = tile + wr * 32 + mi * 16 + lrow;
        grow[mi] = (r < N) ? r : (N - 1);
    }

    f32x4 acc2[2][2];
    #pragma unroll
    for (int mi = 0; mi < 2; ++mi)
        #pragma unroll
        for (int nf = 0; nf < 2; ++nf) acc2[mi][nf] = (f32x4){0.f, 0.f, 0.f, 0.f};

    #pragma unroll
    for (int ks = 0; ks < 8; ++ks) {
        bf16x8 a[2], b[2];
        #pragma unroll
        for (int mi = 0; mi < 2; ++mi) {
            if (ks < 4)
                a[mi] = *(const bf16x8*)(As_s + (wr * 32 + mi * 16 + lrow) * 136 + ks * 32 + lkq * 8);
            else
                a[mi] = *(const bf16x8*)(fb + (size_t)grow[mi] * 128 + (ks - 4) * 32 + lkq * 8);
        }
        #pragma unroll
        for (int nf = 0; nf < 2; ++nf)
            b[nf] = Bp[(ks * 8 + (wc * 2 + nf)) * 64 + lane];
        #pragma unroll
        for (int mi = 0; mi < 2; ++mi)
            #pragma unroll
            for (int nf = 0; nf < 2; ++nf)
                acc2[mi][nf] = __builtin_amdgcn_mfma_f32_16x16x32_bf16(a[mi], b[nf], acc2[mi][nf], 0, 0, 0);
    }

    // ---- epilogue ----
    const int crow = (lane >> 4) * 4;
    const int ccol = lane & 15;
    #pragma unroll
    for (int mi = 0; mi < 2; ++mi) {
        #pragma unroll
        for (int nf = 0; nf < 2; ++nf) {
            const int col = wc * 32 + nf * 16 + ccol;
            const float bv = bias[col];
            #pragma unroll
            for (int r = 0; r < 4; ++r) {
                const int row = tile + wr * 32 + mi * 16 + crow + r;
                if (row < N) {
                    float v = acc2[mi][nf][r] + bv;
                    if (RELU) v = fmaxf(v, 0.f);
                    if (OUTF32) outf[(size_t)row * 128 + col] = v;
                    else        outb[(size_t)row * 128 + col] = __float2bfloat16(v);
                }
            }
        }
    }
}

// ---------------- launch ----------------

extern "C" void kernel_launch(void* const* d_in, const int* in_sizes, int n_in,
                              void* d_out, int out_size, void* d_ws, size_t ws_size,
                              hipStream_t stream) {
    const float* x   = (const float*)d_in[0];
    const int*  eidx = (const int*)d_in[1];
    const float* ew  = (const float*)d_in[2];
    const float* w1r = (const float*)d_in[3];
    const float* w1t = (const float*)d_in[4];
    const float* b1  = (const float*)d_in[5];
    const float* w2r = (const float*)d_in[6];
    const float* w2t = (const float*)d_in[7];
    const float* b2  = (const float*)d_in[8];
    const float* w3r = (const float*)d_in[9];
    const float* w3t = (const float*)d_in[10];
    const float* b3  = (const float*)d_in[11];
    float* out = (float*)d_out;

    const int N  = in_sizes[0] / DFEAT;   // 50000
    const int E  = in_sizes[2];           // 800000
    const int NB = (N + 63) / 64;         // 782 buckets

    char* ws = (char*)d_ws;
    size_t off = 0;
    auto alloc = [&](size_t bytes) -> void* {
        off = (off + 255) & ~(size_t)255;
        void* p = ws + off;
        off += bytes;
        return p;
    };
    int*  cursor = (int*)alloc((size_t)NB * 4);
    int*  rowptr = (int*)alloc((size_t)N * 4);
    int*  rowend = (int*)alloc((size_t)N * 4);
    int2* bedges = (int2*)alloc((size_t)NB * BCAP * 8);   // 12.8 MB
    __hip_bfloat16* Bp1 = (__hip_bfloat16*)alloc(32768 * 2);
    __hip_bfloat16* Bp2 = (__hip_bfloat16*)alloc(32768 * 2);
    __hip_bfloat16* Bp3 = (__hip_bfloat16*)alloc(32768 * 2);
    uint* xb   = (uint*)alloc((size_t)N * 64 * 4);
    uint* h1b  = (uint*)alloc((size_t)N * 64 * 4);
    uint* h2b  = (uint*)alloc((size_t)N * 64 * 4);
    (void)ws_size;

    const int* src = eidx;
    const int* dst = eidx + E;

    // merged prep: cvt + weight pack + cursor init
    const int n2 = N * 64;
    const int cvtB = (n2 + 255) / 256;
    const int curB = (NB + 255) / 256;
    prep_all<<<cvtB + 384 + curB, 256, 0, stream>>>(x, xb, n2,
                                                    w1r, w1t, w2r, w2t, w3r, w3t,
                                                    Bp1, Bp2, Bp3, cursor, NB, cvtB);

    // CSR build: bucket scatter + per-bucket counting sort
    bin_scatter<<<(E + 8191) / 8192, 1024, 0, stream>>>(src, dst, ew, cursor, bedges, E, NB);
    bucket_sort<<<NB, 1024, 0, stream>>>(cursor, bedges, rowptr, rowend, N);

    // fused layers (64-node tiles, 8 waves)
    fused_layer<1, 0><<<NB, 512, 0, stream>>>(xb, rowptr, rowend, bedges, (const bf16x8*)Bp1,
                                              b1, nullptr, (__hip_bfloat16*)h1b, N);
    fused_layer<1, 0><<<NB, 512, 0, stream>>>(h1b, rowptr, rowend, bedges, (const bf16x8*)Bp2,
                                              b2, nullptr, (__hip_bfloat16*)h2b, N);
    fused_layer<0, 1><<<NB, 512, 0, stream>>>(h2b, rowptr, rowend, bedges, (const bf16x8*)Bp3,
                                              b3, out, nullptr, N);
}